// Round 1
// baseline (733.678 us; speedup 1.0000x reference)
//
#include <hip/hip_runtime.h>

// EmbeddingLSQ: out[t,d] = (idx[t]==0) ? 0 : round(clamp(W[d,idx[t]]/a,-8,7))*a
// where idx[t] = argmax over one-hot row x[t,:].
//
// Strategy: 1 block (256 thr) per token.
//   Phase 1: float4 scan of x row (32000 floats) with shared-flag early exit
//            (one-hot => unique element > 0.5; expected half-row scan).
//   Phase 2: strided gather of W column idx, fp32 LSQ fake-quant, coalesced
//            write of the 1024-wide output row.

constexpr int VOCAB  = 32000;
constexpr int DIM    = 1024;
constexpr int TOKENS = 4096;
constexpr int V4     = VOCAB / 4;   // 8000 float4 per row
constexpr int BLOCK  = 256;

__global__ __launch_bounds__(BLOCK) void emb_lsq_kernel(
    const float* __restrict__ x,
    const float* __restrict__ w,
    const float* __restrict__ alpha,
    float* __restrict__ out)
{
    const int t   = blockIdx.x;
    const int tid = threadIdx.x;

    __shared__ volatile int s_idx;
    if (tid == 0) s_idx = -1;
    __syncthreads();

    // ---- Phase 1: find the one-hot index in x[t, :] ----
    const float4* xr = reinterpret_cast<const float4*>(x + (size_t)t * VOCAB);
    for (int i = tid; i < V4; i += BLOCK) {
        float4 v = xr[i];
        int found = -1;
        if      (v.x > 0.5f) found = 4 * i + 0;
        else if (v.y > 0.5f) found = 4 * i + 1;
        else if (v.z > 0.5f) found = 4 * i + 2;
        else if (v.w > 0.5f) found = 4 * i + 3;
        if (found >= 0) s_idx = found;       // at most one thread ever writes
        if (s_idx >= 0) break;               // early exit once anyone found it
    }
    __syncthreads();
    const int idx = s_idx;

    // ---- Phase 2: gather + LSQ fake-quant + coalesced row write ----
    float* orow = out + (size_t)t * DIM;
    if (idx == 0) {                          // PAD_IDX -> zero row
        for (int d = tid; d < DIM; d += BLOCK) orow[d] = 0.0f;
    } else {
        const float a = alpha[0];
        for (int d = tid; d < DIM; d += BLOCK) {
            float wv = w[(size_t)d * VOCAB + idx];
            float q  = rintf(fminf(fmaxf(wv / a, -8.0f), 7.0f)) * a;  // round-half-even, like jnp.round
            orow[d]  = q;
        }
    }
}

extern "C" void kernel_launch(void* const* d_in, const int* in_sizes, int n_in,
                              void* d_out, int out_size, void* d_ws, size_t ws_size,
                              hipStream_t stream) {
    const float* x     = (const float*)d_in[0];   // [TOKENS, VOCAB]
    const float* w     = (const float*)d_in[1];   // [DIM, VOCAB]
    const float* alpha = (const float*)d_in[2];   // [1]
    float* out         = (float*)d_out;           // [TOKENS, DIM]

    emb_lsq_kernel<<<TOKENS, BLOCK, 0, stream>>>(x, w, alpha, out);
}